// Round 1
// baseline (263.219 us; speedup 1.0000x reference)
//
#include <hip/hip_runtime.h>

#define NROWS 8192
#define DDIM 512
#define ZROWS 16384
#define BM 128
#define BN 128
#define BK 64
#define NTILE_M (NROWS / BM)   // 64
#define NTILE_N (ZROWS / BN)   // 128

typedef __attribute__((ext_vector_type(8))) short short8;
typedef __attribute__((ext_vector_type(4))) float f32x4;

__device__ __forceinline__ unsigned short f2bf(float f) {
  unsigned int u = __float_as_uint(f);
  u = (u + 0x7FFFu + ((u >> 16) & 1u)) >> 16;
  return (unsigned short)u;
}

// Kernel 1: per-row L2 normalize both inputs, write bf16 Z = [zl; zr],
// and compute the fp32 diagonal cosine sim dlr[i] = zl_i . zr_i.
__global__ __launch_bounds__(256) void nrm_kernel(const float* __restrict__ left,
                                                  const float* __restrict__ right,
                                                  unsigned short* __restrict__ Z,
                                                  float* __restrict__ dlr) {
  const int i = blockIdx.x;
  const int t = threadIdx.x;
  const float2 lv = ((const float2*)(left + (size_t)i * DDIM))[t];
  const float2 rv = ((const float2*)(right + (size_t)i * DDIM))[t];
  float ssl = lv.x * lv.x + lv.y * lv.y;
  float ssr = rv.x * rv.x + rv.y * rv.y;
  float slr = lv.x * rv.x + lv.y * rv.y;
#pragma unroll
  for (int m = 1; m < 64; m <<= 1) {
    ssl += __shfl_xor(ssl, m);
    ssr += __shfl_xor(ssr, m);
    slr += __shfl_xor(slr, m);
  }
  __shared__ float red[3][4];
  const int w = t >> 6;
  if ((t & 63) == 0) { red[0][w] = ssl; red[1][w] = ssr; red[2][w] = slr; }
  __syncthreads();
  ssl = red[0][0] + red[0][1] + red[0][2] + red[0][3];
  ssr = red[1][0] + red[1][1] + red[1][2] + red[1][3];
  slr = red[2][0] + red[2][1] + red[2][2] + red[2][3];
  const float invl = 1.0f / fmaxf(sqrtf(ssl), 1e-12f);
  const float invr = 1.0f / fmaxf(sqrtf(ssr), 1e-12f);
  if (t == 0) dlr[i] = slr * invl * invr;
  ushort2 zl2; zl2.x = f2bf(lv.x * invl); zl2.y = f2bf(lv.y * invl);
  ushort2 zr2; zr2.x = f2bf(rv.x * invr); zr2.y = f2bf(rv.y * invr);
  ((ushort2*)(Z + (size_t)i * DDIM))[t] = zl2;
  ((ushort2*)(Z + (size_t)(NROWS + i) * DDIM))[t] = zr2;
}

// Kernel 2: fused GEMM + exp-rowsum. C-tile (BM x BN) of S = ZL . Z^T,
// epilogue computes sum_j exp(2*s_ij) per row into partial[tn][global_row].
// m97 structure: 128x128 tile, BK=64, 4 waves (2x2), 16x16x32 bf16 MFMA,
// global_load_lds width 16, single-buffered 2-barrier K-loop.
__global__ __launch_bounds__(256) void sim_kernel(const unsigned short* __restrict__ Z,
                                                  float* __restrict__ partial) {
  __shared__ __align__(16) unsigned short sA[BM * BK];
  __shared__ __align__(16) unsigned short sB[BN * BK];
  __shared__ float rsum[BM];

  const int tm = blockIdx.x;
  const int tn = blockIdx.y;
  const int t = threadIdx.x;
  const int w = t >> 6;
  const int l = t & 63;
  const int wr = w >> 1;   // wave row 0..1 (64-row slab)
  const int wc = w & 1;    // wave col 0..1 (64-col slab)
  const int lr = l & 15;
  const int lk = l >> 4;   // 0..3

  f32x4 acc[4][4];
#pragma unroll
  for (int a = 0; a < 4; ++a)
#pragma unroll
    for (int b = 0; b < 4; ++b)
#pragma unroll
      for (int r = 0; r < 4; ++r) acc[a][b][r] = 0.0f;

  const unsigned short* Abase = Z + (size_t)tm * BM * DDIM;
  const unsigned short* Bbase = Z + (size_t)tn * BN * DDIM;

  for (int k0 = 0; k0 < DDIM; k0 += BK) {
    // Stage A and B tiles: 128 rows x 64 k, 16B per lane, linear LDS layout.
    // element e = is*256 + t; row = e>>3; kcol = (e&7)*8; LDS byte = e*16.
#pragma unroll
    for (int is = 0; is < 4; ++is) {
      const int e = is * 256 + t;
      const int row = e >> 3;
      const int kc = (e & 7) * 8;
      __builtin_amdgcn_global_load_lds(
          (const __attribute__((address_space(1))) void*)(Abase + (size_t)row * DDIM + k0 + kc),
          (__attribute__((address_space(3))) void*)(&sA[(size_t)(is * 256 + w * 64) * 8]),
          16, 0, 0);
      __builtin_amdgcn_global_load_lds(
          (const __attribute__((address_space(1))) void*)(Bbase + (size_t)row * DDIM + k0 + kc),
          (__attribute__((address_space(3))) void*)(&sB[(size_t)(is * 256 + w * 64) * 8]),
          16, 0, 0);
    }
    __syncthreads();
#pragma unroll
    for (int kk = 0; kk < 2; ++kk) {
      short8 af[4], bfr[4];
#pragma unroll
      for (int fm = 0; fm < 4; ++fm)
        af[fm] = *(const short8*)&sA[(wr * 64 + fm * 16 + lr) * BK + kk * 32 + lk * 8];
#pragma unroll
      for (int fn = 0; fn < 4; ++fn)
        bfr[fn] = *(const short8*)&sB[(wc * 64 + fn * 16 + lr) * BK + kk * 32 + lk * 8];
#pragma unroll
      for (int fm = 0; fm < 4; ++fm)
#pragma unroll
        for (int fn = 0; fn < 4; ++fn)
          acc[fm][fn] = __builtin_amdgcn_mfma_f32_16x16x32_bf16(af[fm], bfr[fn], acc[fm][fn], 0, 0, 0);
    }
    __syncthreads();
  }

  // Epilogue: v = exp(2*s); row-sum across the 128 cols of this block.
  // C/D layout (16x16x32): col = lane&15, row = (lane>>4)*4 + reg.
  if (t < BM) rsum[t] = 0.0f;
  __syncthreads();
#pragma unroll
  for (int fm = 0; fm < 4; ++fm) {
#pragma unroll
    for (int r = 0; r < 4; ++r) {
      float v = __expf(2.0f * acc[fm][0][r]) + __expf(2.0f * acc[fm][1][r]) +
                __expf(2.0f * acc[fm][2][r]) + __expf(2.0f * acc[fm][3][r]);
      v += __shfl_xor(v, 1);
      v += __shfl_xor(v, 2);
      v += __shfl_xor(v, 4);
      v += __shfl_xor(v, 8);
      if (lr == 0) atomicAdd(&rsum[wr * 64 + fm * 16 + lk * 4 + r], v);
    }
  }
  __syncthreads();
  if (t < BM) partial[(size_t)tn * NROWS + (size_t)tm * BM + t] = rsum[t];
}

// Kernel 3: reduce partials, final loss.
// loss[i] = log(rowsum - e^2) - 2*dlr[i]
__global__ __launch_bounds__(256) void fin_kernel(const float* __restrict__ partial,
                                                  const float* __restrict__ dlr,
                                                  float* __restrict__ out) {
  const int i = blockIdx.x * 256 + threadIdx.x;
  float s = 0.0f;
#pragma unroll 8
  for (int p = 0; p < NTILE_N; ++p) s += partial[(size_t)p * NROWS + i];
  out[i] = logf(s - 7.38905609893065f) - 2.0f * dlr[i];
}

extern "C" void kernel_launch(void* const* d_in, const int* in_sizes, int n_in,
                              void* d_out, int out_size, void* d_ws, size_t ws_size,
                              hipStream_t stream) {
  const float* left = (const float*)d_in[0];
  const float* right = (const float*)d_in[1];
  float* out = (float*)d_out;

  unsigned short* Z = (unsigned short*)d_ws;                       // 16384*512*2 = 16 MB
  char* p = (char*)d_ws + (size_t)ZROWS * DDIM * 2;
  float* dlr = (float*)p;                                          // 32 KB
  float* partial = (float*)(p + (size_t)NROWS * 4);                // 128*8192*4 = 4 MB

  nrm_kernel<<<NROWS, 256, 0, stream>>>(left, right, Z, dlr);
  dim3 g(NTILE_M, NTILE_N);
  sim_kernel<<<g, 256, 0, stream>>>(Z, partial);
  fin_kernel<<<NROWS / 256, 256, 0, stream>>>(partial, dlr, out);
}

// Round 2
// 204.851 us; speedup vs baseline: 1.2849x; 1.2849x over previous
//
#include <hip/hip_runtime.h>

#define NROWS 8192
#define DDIM 512
#define ZROWS 16384
#define BM 128
#define BN 128
#define BK 64
#define KTILES (DDIM / BK)     // 8
#define NTILE_M (NROWS / BM)   // 64
#define NTILE_N (ZROWS / BN)   // 128

typedef __attribute__((ext_vector_type(8))) short short8;
typedef __attribute__((ext_vector_type(4))) float f32x4;

__device__ __forceinline__ unsigned short f2bf(float f) {
  unsigned int u = __float_as_uint(f);
  u = (u + 0x7FFFu + ((u >> 16) & 1u)) >> 16;
  return (unsigned short)u;
}

// Kernel 1: per-row L2 normalize both inputs, write bf16 Z = [zl; zr],
// and compute the fp32 diagonal cosine sim dlr[i] = zl_i . zr_i.
__global__ __launch_bounds__(256) void nrm_kernel(const float* __restrict__ left,
                                                  const float* __restrict__ right,
                                                  unsigned short* __restrict__ Z,
                                                  float* __restrict__ dlr) {
  const int i = blockIdx.x;
  const int t = threadIdx.x;
  const float2 lv = ((const float2*)(left + (size_t)i * DDIM))[t];
  const float2 rv = ((const float2*)(right + (size_t)i * DDIM))[t];
  float ssl = lv.x * lv.x + lv.y * lv.y;
  float ssr = rv.x * rv.x + rv.y * rv.y;
  float slr = lv.x * rv.x + lv.y * rv.y;
#pragma unroll
  for (int m = 1; m < 64; m <<= 1) {
    ssl += __shfl_xor(ssl, m);
    ssr += __shfl_xor(ssr, m);
    slr += __shfl_xor(slr, m);
  }
  __shared__ float red[3][4];
  const int w = t >> 6;
  if ((t & 63) == 0) { red[0][w] = ssl; red[1][w] = ssr; red[2][w] = slr; }
  __syncthreads();
  ssl = red[0][0] + red[0][1] + red[0][2] + red[0][3];
  ssr = red[1][0] + red[1][1] + red[1][2] + red[1][3];
  slr = red[2][0] + red[2][1] + red[2][2] + red[2][3];
  const float invl = 1.0f / fmaxf(sqrtf(ssl), 1e-12f);
  const float invr = 1.0f / fmaxf(sqrtf(ssr), 1e-12f);
  if (t == 0) dlr[i] = slr * invl * invr;
  ushort2 zl2; zl2.x = f2bf(lv.x * invl); zl2.y = f2bf(lv.y * invl);
  ushort2 zr2; zr2.x = f2bf(rv.x * invr); zr2.y = f2bf(rv.y * invr);
  ((ushort2*)(Z + (size_t)i * DDIM))[t] = zl2;
  ((ushort2*)(Z + (size_t)(NROWS + i) * DDIM))[t] = zr2;
}

// Kernel 2: fused GEMM + exp-rowsum, 128x128 tile, BK=64, 4 waves (2x2).
// T2: XOR-swizzled LDS (linear global_load_lds dest + pre-swizzled global
// source slot + matching XOR on ds_read address).
// T3/T4-min: double-buffered LDS, next-tile prefetch issued BEFORE compute,
// counted s_waitcnt vmcnt(8) + raw s_barrier (no vmcnt(0) drain in loop).
__global__ __launch_bounds__(256) void sim_kernel(const unsigned short* __restrict__ Z,
                                                  float* __restrict__ partial) {
  __shared__ __align__(16) unsigned short sA[2][BM * BK];
  __shared__ __align__(16) unsigned short sB[2][BN * BK];
  __shared__ float rsum[BM];

  const int tm = blockIdx.x;
  const int tn = blockIdx.y;
  const int t = threadIdx.x;
  const int w = t >> 6;
  const int l = t & 63;
  const int wr = w >> 1;   // wave row 0..1 (64-row slab)
  const int wc = w & 1;    // wave col 0..1 (64-col slab)
  const int lr = l & 15;
  const int lk = l >> 4;   // 0..3

  if (t < BM) rsum[t] = 0.0f;   // visible before any atomicAdd (>=2 barriers later)

  f32x4 acc[4][4];
#pragma unroll
  for (int a = 0; a < 4; ++a)
#pragma unroll
    for (int b = 0; b < 4; ++b)
#pragma unroll
      for (int r = 0; r < 4; ++r) acc[a][b][r] = 0.0f;

  const unsigned short* Abase = Z + (size_t)tm * BM * DDIM;
  const unsigned short* Bbase = Z + (size_t)tn * BN * DDIM;

  // Staging geometry: element e = is*256 + t; LDS gets e-th 16B slot linearly
  // (lds row = e>>3, lds slot = e&7). Pre-swizzle the GLOBAL slot so that
  // LDS[row][slot] holds global slot (slot ^ (row&7)).
  const int srow = t >> 3;                          // row within 32-row group
  const int scol = ((t & 7) ^ (srow & 7)) * 8;      // swizzled element offset

#define STAGE(buf, k0)                                                           \
  {                                                                              \
    _Pragma("unroll")                                                            \
    for (int is = 0; is < 4; ++is) {                                             \
      __builtin_amdgcn_global_load_lds(                                          \
          (const __attribute__((address_space(1))) void*)(Abase +                \
              (size_t)(is * 32 + srow) * DDIM + (k0) + scol),                    \
          (__attribute__((address_space(3))) void*)(&sA[buf][(is * 256 + w * 64) * 8]), \
          16, 0, 0);                                                             \
      __builtin_amdgcn_global_load_lds(                                          \
          (const __attribute__((address_space(1))) void*)(Bbase +                \
              (size_t)(is * 32 + srow) * DDIM + (k0) + scol),                    \
          (__attribute__((address_space(3))) void*)(&sB[buf][(is * 256 + w * 64) * 8]), \
          16, 0, 0);                                                             \
    }                                                                            \
  }

  STAGE(0, 0);

#pragma unroll
  for (int kt = 0; kt < KTILES; ++kt) {
    const int cur = kt & 1;
    if (kt + 1 < KTILES) {
      STAGE(cur ^ 1, (kt + 1) * BK);
      asm volatile("s_waitcnt vmcnt(8)" ::: "memory");  // wait only the 8 older (buf cur) loads
    } else {
      asm volatile("s_waitcnt vmcnt(0)" ::: "memory");
    }
    __builtin_amdgcn_s_barrier();
    __builtin_amdgcn_sched_barrier(0);   // no ds_read hoists above the barrier

#pragma unroll
    for (int kk = 0; kk < 2; ++kk) {
      short8 af[4], bfr[4];
#pragma unroll
      for (int fm = 0; fm < 4; ++fm) {
        const int row = wr * 64 + fm * 16 + lr;
        const int ps = ((kk * 4 + lk) ^ (lr & 7)) * 8;   // swizzled slot
        af[fm] = *(const short8*)&sA[cur][row * BK + ps];
      }
#pragma unroll
      for (int fn = 0; fn < 4; ++fn) {
        const int row = wc * 64 + fn * 16 + lr;
        const int ps = ((kk * 4 + lk) ^ (lr & 7)) * 8;
        bfr[fn] = *(const short8*)&sB[cur][row * BK + ps];
      }
#pragma unroll
      for (int fm = 0; fm < 4; ++fm)
#pragma unroll
        for (int fn = 0; fn < 4; ++fn)
          acc[fm][fn] = __builtin_amdgcn_mfma_f32_16x16x32_bf16(af[fm], bfr[fn], acc[fm][fn], 0, 0, 0);
    }
    __builtin_amdgcn_sched_barrier(0);   // nothing sinks past / hoists above
    __builtin_amdgcn_s_barrier();
    __builtin_amdgcn_sched_barrier(0);   // next STAGE stays after this barrier
  }

  // Epilogue: v = exp(2*s); row-sum across the 128 cols of this block.
  // C/D layout (16x16x32): col = lane&15, row = (lane>>4)*4 + reg.
#pragma unroll
  for (int fm = 0; fm < 4; ++fm) {
#pragma unroll
    for (int r = 0; r < 4; ++r) {
      float v = __expf(2.0f * acc[fm][0][r]) + __expf(2.0f * acc[fm][1][r]) +
                __expf(2.0f * acc[fm][2][r]) + __expf(2.0f * acc[fm][3][r]);
      v += __shfl_xor(v, 1);
      v += __shfl_xor(v, 2);
      v += __shfl_xor(v, 4);
      v += __shfl_xor(v, 8);
      if (lr == 0) atomicAdd(&rsum[wr * 64 + fm * 16 + lk * 4 + r], v);
    }
  }
  __syncthreads();
  if (t < BM) partial[(size_t)tn * NROWS + (size_t)tm * BM + t] = rsum[t];
}

// Kernel 3: reduce partials, final loss.
// loss[i] = log(rowsum - e^2) - 2*dlr[i]
__global__ __launch_bounds__(256) void fin_kernel(const float* __restrict__ partial,
                                                  const float* __restrict__ dlr,
                                                  float* __restrict__ out) {
  const int i = blockIdx.x * 256 + threadIdx.x;
  float s = 0.0f;
#pragma unroll 8
  for (int p = 0; p < NTILE_N; ++p) s += partial[(size_t)p * NROWS + i];
  out[i] = logf(s - 7.38905609893065f) - 2.0f * dlr[i];
}

extern "C" void kernel_launch(void* const* d_in, const int* in_sizes, int n_in,
                              void* d_out, int out_size, void* d_ws, size_t ws_size,
                              hipStream_t stream) {
  const float* left = (const float*)d_in[0];
  const float* right = (const float*)d_in[1];
  float* out = (float*)d_out;

  unsigned short* Z = (unsigned short*)d_ws;                       // 16 MB
  char* p = (char*)d_ws + (size_t)ZROWS * DDIM * 2;
  float* dlr = (float*)p;                                          // 32 KB
  float* partial = (float*)(p + (size_t)NROWS * 4);                // 4 MB

  nrm_kernel<<<NROWS, 256, 0, stream>>>(left, right, Z, dlr);
  dim3 g(NTILE_M, NTILE_N);
  sim_kernel<<<g, 256, 0, stream>>>(Z, partial);
  fin_kernel<<<NROWS / 256, 256, 0, stream>>>(partial, dlr, out);
}

// Round 3
// 189.854 us; speedup vs baseline: 1.3864x; 1.0790x over previous
//
#include <hip/hip_runtime.h>

#define NROWS 8192
#define DDIM 512
#define ZROWS 16384
#define BM 256
#define BN 256
#define BK 64
#define KTILES (DDIM / BK)     // 8
#define NTILE_M (NROWS / BM)   // 32
#define NTILE_N (ZROWS / BN)   // 64

typedef __attribute__((ext_vector_type(8))) short short8;
typedef __attribute__((ext_vector_type(4))) float f32x4;

__device__ __forceinline__ unsigned short f2bf(float f) {
  unsigned int u = __float_as_uint(f);
  u = (u + 0x7FFFu + ((u >> 16) & 1u)) >> 16;
  return (unsigned short)u;
}

// Kernel 1: per-row L2 normalize both inputs, write bf16 Z = [zl; zr],
// and compute the fp32 diagonal cosine sim dlr[i] = zl_i . zr_i.
__global__ __launch_bounds__(256) void nrm_kernel(const float* __restrict__ left,
                                                  const float* __restrict__ right,
                                                  unsigned short* __restrict__ Z,
                                                  float* __restrict__ dlr) {
  const int i = blockIdx.x;
  const int t = threadIdx.x;
  const float2 lv = ((const float2*)(left + (size_t)i * DDIM))[t];
  const float2 rv = ((const float2*)(right + (size_t)i * DDIM))[t];
  float ssl = lv.x * lv.x + lv.y * lv.y;
  float ssr = rv.x * rv.x + rv.y * rv.y;
  float slr = lv.x * rv.x + lv.y * rv.y;
#pragma unroll
  for (int m = 1; m < 64; m <<= 1) {
    ssl += __shfl_xor(ssl, m);
    ssr += __shfl_xor(ssr, m);
    slr += __shfl_xor(slr, m);
  }
  __shared__ float red[3][4];
  const int w = t >> 6;
  if ((t & 63) == 0) { red[0][w] = ssl; red[1][w] = ssr; red[2][w] = slr; }
  __syncthreads();
  ssl = red[0][0] + red[0][1] + red[0][2] + red[0][3];
  ssr = red[1][0] + red[1][1] + red[1][2] + red[1][3];
  slr = red[2][0] + red[2][1] + red[2][2] + red[2][3];
  const float invl = 1.0f / fmaxf(sqrtf(ssl), 1e-12f);
  const float invr = 1.0f / fmaxf(sqrtf(ssr), 1e-12f);
  if (t == 0) dlr[i] = slr * invl * invr;
  ushort2 zl2; zl2.x = f2bf(lv.x * invl); zl2.y = f2bf(lv.y * invl);
  ushort2 zr2; zr2.x = f2bf(rv.x * invr); zr2.y = f2bf(rv.y * invr);
  ((ushort2*)(Z + (size_t)i * DDIM))[t] = zl2;
  ((ushort2*)(Z + (size_t)(NROWS + i) * DDIM))[t] = zr2;
}

// Kernel 2: fused GEMM + exp-rowsum, 256x256 tile, BK=64, 8 waves (2Mx4N),
// 8-phase schedule (4 phases/K-tile), double-buffered 128 KiB LDS,
// XOR-swizzled staging (linear global_load_lds dest + pre-swizzled global
// source + matching XOR on ds_read), counted vmcnt(2) at K-tile boundary
// only, setprio(1) around each 16-MFMA cluster.
__global__ __launch_bounds__(512, 2) void sim_kernel(const unsigned short* __restrict__ Z,
                                                     float* __restrict__ partial) {
  __shared__ __align__(16) unsigned short sA[2][BM * BK];   // 64 KiB
  __shared__ __align__(16) unsigned short sB[2][BN * BK];   // 64 KiB

  const int tm = blockIdx.x;
  const int tn = blockIdx.y;
  const int t = threadIdx.x;
  const int l = t & 63;
  const int w = t >> 6;        // wave 0..7
  const int wm = w >> 2;       // 0..1  (128-row slab)
  const int wn = w & 3;        // 0..3  (64-col slab)
  const int lr = l & 15;
  const int lk = l >> 4;       // 0..3

  f32x4 acc[8][4];
#pragma unroll
  for (int a = 0; a < 8; ++a)
#pragma unroll
    for (int b = 0; b < 4; ++b)
#pragma unroll
      for (int r = 0; r < 4; ++r) acc[a][b][r] = 0.0f;

  const unsigned short* Abase = Z + (size_t)tm * BM * DDIM;
  const unsigned short* Bbase = Z + (size_t)tn * BN * DDIM;

  // Staging geometry: element e = j*512 + t; LDS slot-linear (row=e>>3,
  // slot=e&7); global source slot pre-swizzled by row&7.
  const int srow = t >> 3;                       // 0..63
  const int scol = ((t & 7) ^ (srow & 7)) * 8;   // swizzled source element col

#define STAGE_HALF(dst, gbase, k0, h)                                             \
  {                                                                               \
    _Pragma("unroll")                                                             \
    for (int j = 2 * (h); j <= 2 * (h) + 1; ++j) {                                \
      __builtin_amdgcn_global_load_lds(                                           \
          (const __attribute__((address_space(1))) void*)((gbase) +               \
              (size_t)(j * 64 + srow) * DDIM + (k0) + scol),                      \
          (__attribute__((address_space(3))) void*)(&(dst)[(j * 512 + t) * 8]),   \
          16, 0, 0);                                                              \
    }                                                                             \
  }

  // prologue: all 4 halves of K-tile 0 into buffer 0 (8 loads/thread)
  STAGE_HALF(sA[0], Abase, 0, 0);
  STAGE_HALF(sA[0], Abase, 0, 1);
  STAGE_HALF(sB[0], Bbase, 0, 0);
  STAGE_HALF(sB[0], Bbase, 0, 1);

  short8 af[4][2], bf[2][2];

#define DS_A(fmb)                                                                  \
  _Pragma("unroll")                                                                \
  for (int fm = 0; fm < 4; ++fm)                                                   \
    _Pragma("unroll")                                                              \
    for (int ks = 0; ks < 2; ++ks) {                                               \
      const int row = wm * 128 + ((fmb) + fm) * 16 + lr;                           \
      af[fm][ks] = *(const short8*)&sA[cur][row * BK + ((ks * 4 + lk) ^ (lr & 7)) * 8]; \
    }

#define DS_B(fnb)                                                                  \
  _Pragma("unroll")                                                                \
  for (int fn = 0; fn < 2; ++fn)                                                   \
    _Pragma("unroll")                                                              \
    for (int ks = 0; ks < 2; ++ks) {                                               \
      const int row = wn * 64 + ((fnb) + fn) * 16 + lr;                            \
      bf[fn][ks] = *(const short8*)&sB[cur][row * BK + ((ks * 4 + lk) ^ (lr & 7)) * 8]; \
    }

#define MFMA16(fmb, fnb)                                                           \
  __builtin_amdgcn_s_setprio(1);                                                   \
  _Pragma("unroll")                                                                \
  for (int fm = 0; fm < 4; ++fm)                                                   \
    _Pragma("unroll")                                                              \
    for (int fn = 0; fn < 2; ++fn)                                                 \
      _Pragma("unroll")                                                            \
      for (int ks = 0; ks < 2; ++ks)                                               \
        acc[(fmb) + fm][(fnb) + fn] =                                              \
            __builtin_amdgcn_mfma_f32_16x16x32_bf16(af[fm][ks], bf[fn][ks],        \
                                                    acc[(fmb) + fm][(fnb) + fn],   \
                                                    0, 0, 0);                      \
  __builtin_amdgcn_s_setprio(0);

#pragma unroll
  for (int kt = 0; kt < KTILES; ++kt) {
    const int cur = kt & 1;
    const int nxt = cur ^ 1;
    // ---- phase 0: M[0..3] x N[0..1]; stage A-half0 of kt+1; boundary vmcnt
    if (kt + 1 < KTILES) {
      STAGE_HALF(sA[nxt], Abase, (kt + 1) * BK, 0);
      asm volatile("s_waitcnt vmcnt(2)" ::: "memory");  // all kt loads done, 2 newest in flight
    } else {
      asm volatile("s_waitcnt vmcnt(0)" ::: "memory");
    }
    __builtin_amdgcn_s_barrier();
    __builtin_amdgcn_sched_barrier(0);   // no ds_read hoists above buffer-ready barrier
    DS_A(0); DS_B(0);
    MFMA16(0, 0);
    __builtin_amdgcn_sched_barrier(0);
    __builtin_amdgcn_s_barrier();
    __builtin_amdgcn_sched_barrier(0);
    // ---- phase 1: M[0..3] x N[2..3]; stage A-half1
    DS_B(2);
    if (kt + 1 < KTILES) STAGE_HALF(sA[nxt], Abase, (kt + 1) * BK, 1);
    __builtin_amdgcn_sched_barrier(0);
    __builtin_amdgcn_s_barrier();
    __builtin_amdgcn_sched_barrier(0);
    MFMA16(0, 2);
    __builtin_amdgcn_sched_barrier(0);
    __builtin_amdgcn_s_barrier();
    __builtin_amdgcn_sched_barrier(0);
    // ---- phase 2: M[4..7] x N[0..1]; stage B-half0
    DS_A(4); DS_B(0);
    if (kt + 1 < KTILES) STAGE_HALF(sB[nxt], Bbase, (kt + 1) * BK, 0);
    __builtin_amdgcn_sched_barrier(0);
    __builtin_amdgcn_s_barrier();
    __builtin_amdgcn_sched_barrier(0);
    MFMA16(4, 0);
    __builtin_amdgcn_sched_barrier(0);
    __builtin_amdgcn_s_barrier();
    __builtin_amdgcn_sched_barrier(0);
    // ---- phase 3: M[4..7] x N[2..3]; stage B-half1
    DS_B(2);
    if (kt + 1 < KTILES) STAGE_HALF(sB[nxt], Bbase, (kt + 1) * BK, 1);
    __builtin_amdgcn_sched_barrier(0);
    __builtin_amdgcn_s_barrier();
    __builtin_amdgcn_sched_barrier(0);
    MFMA16(4, 2);
    __builtin_amdgcn_sched_barrier(0);
    __builtin_amdgcn_s_barrier();
    __builtin_amdgcn_sched_barrier(0);
  }

  // Epilogue: v = exp(2*s); row-sum across this block's 256 cols.
  // C/D layout (16x16x32): col = lane&15, row = (lane>>4)*4 + reg.
  // rsum overlays sA[0] (dead: kt=7 read sA[1]; all DMA drained by vmcnt(0)).
  float* rsum = (float*)&sA[0][0];
  if (t < BM) rsum[t] = 0.0f;
  __syncthreads();
#pragma unroll
  for (int fm = 0; fm < 8; ++fm) {
#pragma unroll
    for (int r = 0; r < 4; ++r) {
      float v = __expf(2.0f * acc[fm][0][r]) + __expf(2.0f * acc[fm][1][r]) +
                __expf(2.0f * acc[fm][2][r]) + __expf(2.0f * acc[fm][3][r]);
      v += __shfl_xor(v, 1);
      v += __shfl_xor(v, 2);
      v += __shfl_xor(v, 4);
      v += __shfl_xor(v, 8);
      if (lr == 0) atomicAdd(&rsum[wm * 128 + fm * 16 + lk * 4 + r], v);
    }
  }
  __syncthreads();
  if (t < BM) partial[(size_t)tn * NROWS + (size_t)tm * BM + t] = rsum[t];
}

// Kernel 3: reduce partials, final loss.
// loss[i] = log(rowsum - e^2) - 2*dlr[i]
__global__ __launch_bounds__(256) void fin_kernel(const float* __restrict__ partial,
                                                  const float* __restrict__ dlr,
                                                  float* __restrict__ out) {
  const int i = blockIdx.x * 256 + threadIdx.x;
  float s = 0.0f;
#pragma unroll 8
  for (int p = 0; p < NTILE_N; ++p) s += partial[(size_t)p * NROWS + i];
  out[i] = logf(s - 7.38905609893065f) - 2.0f * dlr[i];
}

extern "C" void kernel_launch(void* const* d_in, const int* in_sizes, int n_in,
                              void* d_out, int out_size, void* d_ws, size_t ws_size,
                              hipStream_t stream) {
  const float* left = (const float*)d_in[0];
  const float* right = (const float*)d_in[1];
  float* out = (float*)d_out;

  unsigned short* Z = (unsigned short*)d_ws;                       // 16 MB
  char* p = (char*)d_ws + (size_t)ZROWS * DDIM * 2;
  float* dlr = (float*)p;                                          // 32 KB
  float* partial = (float*)(p + (size_t)NROWS * 4);                // 2 MB
  
  nrm_kernel<<<NROWS, 256, 0, stream>>>(left, right, Z, dlr);
  dim3 g(NTILE_M, NTILE_N);
  sim_kernel<<<g, 512, 0, stream>>>(Z, partial);
  fin_kernel<<<NROWS / 256, 256, 0, stream>>>(partial, dlr, out);
}

// Round 4
// 181.968 us; speedup vs baseline: 1.4465x; 1.0433x over previous
//
#include <hip/hip_runtime.h>

#define NROWS 8192
#define DDIM 512
#define ZROWS 16384
#define BM 256
#define BN 256
#define BK 64
#define KTILES (DDIM / BK)     // 8
#define NTILE_M (NROWS / BM)   // 32
#define NTILE_N (ZROWS / BN)   // 64

typedef __attribute__((ext_vector_type(8))) short short8;
typedef __attribute__((ext_vector_type(4))) float f32x4;

__device__ __forceinline__ unsigned short f2bf(float f) {
  unsigned int u = __float_as_uint(f);
  u = (u + 0x7FFFu + ((u >> 16) & 1u)) >> 16;
  return (unsigned short)u;
}

// Kernel 1: per-row L2 normalize both inputs, write bf16 Z = [zl; zr],
// and compute the fp32 diagonal cosine sim dlr[i] = zl_i . zr_i.
__global__ __launch_bounds__(256) void nrm_kernel(const float* __restrict__ left,
                                                  const float* __restrict__ right,
                                                  unsigned short* __restrict__ Z,
                                                  float* __restrict__ dlr) {
  const int i = blockIdx.x;
  const int t = threadIdx.x;
  const float2 lv = ((const float2*)(left + (size_t)i * DDIM))[t];
  const float2 rv = ((const float2*)(right + (size_t)i * DDIM))[t];
  float ssl = lv.x * lv.x + lv.y * lv.y;
  float ssr = rv.x * rv.x + rv.y * rv.y;
  float slr = lv.x * rv.x + lv.y * rv.y;
#pragma unroll
  for (int m = 1; m < 64; m <<= 1) {
    ssl += __shfl_xor(ssl, m);
    ssr += __shfl_xor(ssr, m);
    slr += __shfl_xor(slr, m);
  }
  __shared__ float red[3][4];
  const int w = t >> 6;
  if ((t & 63) == 0) { red[0][w] = ssl; red[1][w] = ssr; red[2][w] = slr; }
  __syncthreads();
  ssl = red[0][0] + red[0][1] + red[0][2] + red[0][3];
  ssr = red[1][0] + red[1][1] + red[1][2] + red[1][3];
  slr = red[2][0] + red[2][1] + red[2][2] + red[2][3];
  const float invl = 1.0f / fmaxf(sqrtf(ssl), 1e-12f);
  const float invr = 1.0f / fmaxf(sqrtf(ssr), 1e-12f);
  if (t == 0) dlr[i] = slr * invl * invr;
  ushort2 zl2; zl2.x = f2bf(lv.x * invl); zl2.y = f2bf(lv.y * invl);
  ushort2 zr2; zr2.x = f2bf(rv.x * invr); zr2.y = f2bf(rv.y * invr);
  ((ushort2*)(Z + (size_t)i * DDIM))[t] = zl2;
  ((ushort2*)(Z + (size_t)(NROWS + i) * DDIM))[t] = zr2;
}

// Kernel 2: fused GEMM + exp-rowsum, 256x256 tile, BK=64, 8 waves (2Mx4N),
// 4 phases/K-tile, double-buffered 128 KiB LDS, XOR-swizzled staging.
// Template-faithful schedule: all 8 global_load_lds for kt+1 issued at kt's
// phase 0 (full-kt latency cover, vmcnt(8) boundary wait); ds_reads for
// phases 1/2 issued BEFORE their leading barrier (buffer valid since kt
// start, latency hides under barrier wait); all A+B frags retained in VGPRs
// (24 ds_read_b128/kt/wave); setprio(1) around each 16-MFMA cluster.
__global__ __launch_bounds__(512) void sim_kernel(const unsigned short* __restrict__ Z,
                                                  float* __restrict__ partial) {
  __shared__ __align__(16) unsigned short sA[2][BM * BK];   // 64 KiB
  __shared__ __align__(16) unsigned short sB[2][BN * BK];   // 64 KiB

  const int tm = blockIdx.x;
  const int tn = blockIdx.y;
  const int t = threadIdx.x;
  const int l = t & 63;
  const int w = t >> 6;        // wave 0..7
  const int wm = w >> 2;       // 0..1  (128-row slab)
  const int wn = w & 3;        // 0..3  (64-col slab)
  const int lr = l & 15;
  const int lk = l >> 4;       // 0..3

  f32x4 acc[8][4];
#pragma unroll
  for (int a = 0; a < 8; ++a)
#pragma unroll
    for (int b = 0; b < 4; ++b)
#pragma unroll
      for (int r = 0; r < 4; ++r) acc[a][b][r] = 0.0f;

  const unsigned short* Abase = Z + (size_t)tm * BM * DDIM;
  const unsigned short* Bbase = Z + (size_t)tn * BN * DDIM;

  // Staging geometry: element e = j*512 + t; LDS slot-linear (row=e>>3,
  // slot=e&7); global source slot pre-swizzled by row&7 so the matching
  // XOR on ds_read is conflict-free (verified: SQ_LDS_BANK_CONFLICT = 0).
  const int srow = t >> 3;                       // 0..63
  const int scol = ((t & 7) ^ (srow & 7)) * 8;   // swizzled source element col

  // All 8 loads (A then B) for K-tile at offset k0 into buffer dst.
#define STAGE8(bufi, k0)                                                          \
  {                                                                               \
    _Pragma("unroll")                                                             \
    for (int j = 0; j < 4; ++j) {                                                 \
      __builtin_amdgcn_global_load_lds(                                           \
          (const __attribute__((address_space(1))) void*)(Abase +                 \
              (size_t)(j * 64 + srow) * DDIM + (k0) + scol),                      \
          (__attribute__((address_space(3))) void*)(&sA[bufi][(j * 512 + t) * 8]),\
          16, 0, 0);                                                              \
    }                                                                             \
    _Pragma("unroll")                                                             \
    for (int j = 0; j < 4; ++j) {                                                 \
      __builtin_amdgcn_global_load_lds(                                           \
          (const __attribute__((address_space(1))) void*)(Bbase +                 \
              (size_t)(j * 64 + srow) * DDIM + (k0) + scol),                      \
          (__attribute__((address_space(3))) void*)(&sB[bufi][(j * 512 + t) * 8]),\
          16, 0, 0);                                                              \
    }                                                                             \
  }

  // prologue: K-tile 0 into buffer 0
  STAGE8(0, 0);

  short8 af[4][2], ag[4][2], bf[4][2];

#define DS_A(dst, fmb)                                                             \
  _Pragma("unroll")                                                                \
  for (int fm = 0; fm < 4; ++fm)                                                   \
    _Pragma("unroll")                                                              \
    for (int ks = 0; ks < 2; ++ks) {                                               \
      const int row = wm * 128 + ((fmb) + fm) * 16 + lr;                           \
      dst[fm][ks] = *(const short8*)&sA[cur][row * BK + ((ks * 4 + lk) ^ (lr & 7)) * 8]; \
    }

#define DS_B2(fnb)                                                                 \
  _Pragma("unroll")                                                                \
  for (int fn = 0; fn < 2; ++fn)                                                   \
    _Pragma("unroll")                                                              \
    for (int ks = 0; ks < 2; ++ks) {                                               \
      const int row = wn * 64 + ((fnb) + fn) * 16 + lr;                            \
      bf[(fnb) + fn][ks] = *(const short8*)&sB[cur][row * BK + ((ks * 4 + lk) ^ (lr & 7)) * 8]; \
    }

#define MFMA16(A, fmb, fnb)                                                        \
  __builtin_amdgcn_s_setprio(1);                                                   \
  _Pragma("unroll")                                                                \
  for (int fm = 0; fm < 4; ++fm)                                                   \
    _Pragma("unroll")                                                              \
    for (int fn = 0; fn < 2; ++fn)                                                 \
      _Pragma("unroll")                                                            \
      for (int ks = 0; ks < 2; ++ks)                                               \
        acc[(fmb) + fm][(fnb) + fn] =                                              \
            __builtin_amdgcn_mfma_f32_16x16x32_bf16(A[fm][ks], bf[(fnb) + fn][ks], \
                                                    acc[(fmb) + fm][(fnb) + fn],   \
                                                    0, 0, 0);                      \
  __builtin_amdgcn_s_setprio(0);

#define SBAR __builtin_amdgcn_sched_barrier(0)

#pragma unroll
  for (int kt = 0; kt < KTILES; ++kt) {
    const int cur = kt & 1;
    const int nxt = cur ^ 1;
    // ---- phase 0: stage ALL of kt+1; boundary wait; quadrant M[0..3]xN[0..1]
    if (kt + 1 < KTILES) {
      STAGE8(nxt, (kt + 1) * BK);
      SBAR;
      asm volatile("s_waitcnt vmcnt(8)" ::: "memory");  // drain kt's 8, keep kt+1's 8 in flight
    } else {
      asm volatile("s_waitcnt vmcnt(0)" ::: "memory");
    }
    __builtin_amdgcn_s_barrier();
    SBAR;                      // no ds_read hoists above validity barrier
    DS_A(af, 0); DS_B2(0);     // 12 reads (exposed; staggered completion + setprio)
    MFMA16(af, 0, 0);
    SBAR;
    __builtin_amdgcn_s_barrier();
    SBAR;
    // ---- phase 1: quadrant M[0..3]xN[2..3]; reads issued before lead barrier
    DS_B2(2);                  // 4 reads, latency hides under barrier wait
    SBAR;
    __builtin_amdgcn_s_barrier();
    SBAR;
    MFMA16(af, 0, 2);
    SBAR;
    __builtin_amdgcn_s_barrier();
    SBAR;
    // ---- phase 2: quadrant M[4..7]xN[0..1]; reads issued before lead barrier
    DS_A(ag, 4);               // 8 reads, latency hides under barrier wait
    SBAR;
    __builtin_amdgcn_s_barrier();
    SBAR;
    MFMA16(ag, 4, 0);
    SBAR;
    __builtin_amdgcn_s_barrier();
    SBAR;
    // ---- phase 3: quadrant M[4..7]xN[2..3]; pure MFMA (all frags retained)
    MFMA16(ag, 4, 2);
    SBAR;
    __builtin_amdgcn_s_barrier();
    SBAR;
  }

  // Epilogue: v = exp(2*s); row-sum across this block's 256 cols.
  // C/D layout (16x16x32): col = lane&15, row = (lane>>4)*4 + reg.
  // rsum overlays sA[0] (dead: kt=7 read buffer 1; all DMA drained by vmcnt(0)).
  float* rsum = (float*)&sA[0][0];
  if (t < BM) rsum[t] = 0.0f;
  __syncthreads();
#pragma unroll
  for (int fm = 0; fm < 8; ++fm) {
#pragma unroll
    for (int r = 0; r < 4; ++r) {
      float v = __expf(2.0f * acc[fm][0][r]) + __expf(2.0f * acc[fm][1][r]) +
                __expf(2.0f * acc[fm][2][r]) + __expf(2.0f * acc[fm][3][r]);
      v += __shfl_xor(v, 1);
      v += __shfl_xor(v, 2);
      v += __shfl_xor(v, 4);
      v += __shfl_xor(v, 8);
      if (lr == 0) atomicAdd(&rsum[wm * 128 + fm * 16 + lk * 4 + r], v);
    }
  }
  __syncthreads();
  if (t < BM) partial[(size_t)tn * NROWS + (size_t)tm * BM + t] = rsum[t];
}

// Kernel 3: reduce partials, final loss.
// loss[i] = log(rowsum - e^2) - 2*dlr[i]
__global__ __launch_bounds__(256) void fin_kernel(const float* __restrict__ partial,
                                                  const float* __restrict__ dlr,
                                                  float* __restrict__ out) {
  const int i = blockIdx.x * 256 + threadIdx.x;
  float s = 0.0f;
#pragma unroll 8
  for (int p = 0; p < NTILE_N; ++p) s += partial[(size_t)p * NROWS + i];
  out[i] = logf(s - 7.38905609893065f) - 2.0f * dlr[i];
}

extern "C" void kernel_launch(void* const* d_in, const int* in_sizes, int n_in,
                              void* d_out, int out_size, void* d_ws, size_t ws_size,
                              hipStream_t stream) {
  const float* left = (const float*)d_in[0];
  const float* right = (const float*)d_in[1];
  float* out = (float*)d_out;

  unsigned short* Z = (unsigned short*)d_ws;                       // 16 MB
  char* p = (char*)d_ws + (size_t)ZROWS * DDIM * 2;
  float* dlr = (float*)p;                                          // 32 KB
  float* partial = (float*)(p + (size_t)NROWS * 4);                // 2 MB

  nrm_kernel<<<NROWS, 256, 0, stream>>>(left, right, Z, dlr);
  dim3 g(NTILE_M, NTILE_N);
  sim_kernel<<<g, 512, 0, stream>>>(Z, partial);
  fin_kernel<<<NROWS / 256, 256, 0, stream>>>(partial, dlr, out);
}

// Round 5
// 158.407 us; speedup vs baseline: 1.6617x; 1.1487x over previous
//
#include <hip/hip_runtime.h>

#define NROWS 8192
#define DDIM 512
#define ZROWS 16384
#define BM 256
#define BN 256
#define BK 64
#define KTILES (DDIM / BK)     // 8
#define NLL 32                 // ll panel count (8192/256)
#define NLR_BLOCKS 1024        // 32 x 32 (tm x lr-col-panel)
#define NSYM_BLOCKS 528        // upper triangle incl diag of 32
#define NBLOCKS (NLR_BLOCKS + NSYM_BLOCKS)   // 1552

typedef __attribute__((ext_vector_type(8))) short short8;
typedef __attribute__((ext_vector_type(4))) float f32x4;

__device__ __forceinline__ unsigned short f2bf(float f) {
  unsigned int u = __float_as_uint(f);
  u = (u + 0x7FFFu + ((u >> 16) & 1u)) >> 16;
  return (unsigned short)u;
}

// Kernel 1: per-row L2 normalize both inputs, write bf16 Z = [zl; zr],
// and compute the fp32 diagonal cosine sim dlr[i] = zl_i . zr_i.
__global__ __launch_bounds__(256) void nrm_kernel(const float* __restrict__ left,
                                                  const float* __restrict__ right,
                                                  unsigned short* __restrict__ Z,
                                                  float* __restrict__ dlr) {
  const int i = blockIdx.x;
  const int t = threadIdx.x;
  const float2 lv = ((const float2*)(left + (size_t)i * DDIM))[t];
  const float2 rv = ((const float2*)(right + (size_t)i * DDIM))[t];
  float ssl = lv.x * lv.x + lv.y * lv.y;
  float ssr = rv.x * rv.x + rv.y * rv.y;
  float slr = lv.x * rv.x + lv.y * rv.y;
#pragma unroll
  for (int m = 1; m < 64; m <<= 1) {
    ssl += __shfl_xor(ssl, m);
    ssr += __shfl_xor(ssr, m);
    slr += __shfl_xor(slr, m);
  }
  __shared__ float red[3][4];
  const int w = t >> 6;
  if ((t & 63) == 0) { red[0][w] = ssl; red[1][w] = ssr; red[2][w] = slr; }
  __syncthreads();
  ssl = red[0][0] + red[0][1] + red[0][2] + red[0][3];
  ssr = red[1][0] + red[1][1] + red[1][2] + red[1][3];
  slr = red[2][0] + red[2][1] + red[2][2] + red[2][3];
  const float invl = 1.0f / fmaxf(sqrtf(ssl), 1e-12f);
  const float invr = 1.0f / fmaxf(sqrtf(ssr), 1e-12f);
  if (t == 0) dlr[i] = slr * invl * invr;
  ushort2 zl2; zl2.x = f2bf(lv.x * invl); zl2.y = f2bf(lv.y * invl);
  ushort2 zr2; zr2.x = f2bf(rv.x * invr); zr2.y = f2bf(rv.y * invr);
  ((ushort2*)(Z + (size_t)i * DDIM))[t] = zl2;
  ((ushort2*)(Z + (size_t)(NROWS + i) * DDIM))[t] = zr2;
}

// Kernel 2: fused GEMM + exp-rowsum with ll-symmetry.
// Blocks: bid<1024 -> lr region (tm in [0,32), tn in [32,64)), rowsum only.
//         else     -> ll upper triangle (tm<=tn<32); off-diag blocks credit
//                     rowsums to slot tn (tm-panel rows) AND colsums to slot
//                     tm (tn-panel rows) — exact by s_ij = s_ji.
// Schedule: 4 phases/kt, every phase's ds_reads pre-barrier; kt+1 staged at
// P0(A)/P1(B); vmcnt(0) at P3 (2-3 phases of cover); P3 trailing barrier is
// the buffer-validity point so kt+1 P0 reads are legal pre-barrier.
__global__ __launch_bounds__(512) void sim_kernel(const unsigned short* __restrict__ Z,
                                                  float* __restrict__ partial) {
  __shared__ __align__(16) unsigned short sA[2][BM * BK];   // 64 KiB
  __shared__ __align__(16) unsigned short sB[2][BN * BK];   // 64 KiB

  // ---- block decode
  int tm, tn; bool sym = false;
  {
    const int bid = blockIdx.x;
    if (bid < NLR_BLOCKS) {
      tm = bid >> 5; tn = 32 + (bid & 31);
    } else {
      const int b2 = bid - NLR_BLOCKS;            // 0..527
      int i = (int)(32.5f - sqrtf(32.5f * 32.5f - 2.0f * (float)b2));
      if (i < 0) i = 0; if (i > 31) i = 31;
      while (i > 0 && (32 * i - i * (i - 1) / 2) > b2) --i;
      while (i < 31 && (32 * (i + 1) - (i + 1) * i / 2) <= b2) ++i;
      tm = i; tn = i + (b2 - (32 * i - i * (i - 1) / 2));
      sym = (tn != tm);
    }
  }

  const int t = threadIdx.x;
  const int l = t & 63;
  const int w = t >> 6;        // wave 0..7
  const int wm = w >> 2;       // 0..1  (128-row slab)
  const int wn = w & 3;        // 0..3  (64-col slab)
  const int lr = l & 15;
  const int lk = l >> 4;       // 0..3

  f32x4 acc[8][4];
#pragma unroll
  for (int a = 0; a < 8; ++a)
#pragma unroll
    for (int b = 0; b < 4; ++b)
#pragma unroll
      for (int r = 0; r < 4; ++r) acc[a][b][r] = 0.0f;

  const unsigned short* Abase = Z + (size_t)tm * BM * DDIM;
  const unsigned short* Bbase = Z + (size_t)tn * BN * DDIM;

  // Staging: element e = j*512 + t; LDS slot-linear; global source slot
  // pre-swizzled by row&7; matching XOR on ds_read (verified conflict-free).
  const int srow = t >> 3;                       // 0..63
  const int scol = ((t & 7) ^ (srow & 7)) * 8;   // swizzled source element col

#define STAGE_A(bufi, k0)                                                         \
  {                                                                               \
    _Pragma("unroll")                                                             \
    for (int j = 0; j < 4; ++j) {                                                 \
      __builtin_amdgcn_global_load_lds(                                           \
          (const __attribute__((address_space(1))) void*)(Abase +                 \
              (size_t)(j * 64 + srow) * DDIM + (k0) + scol),                      \
          (__attribute__((address_space(3))) void*)(&sA[bufi][(j * 512 + t) * 8]),\
          16, 0, 0);                                                              \
    }                                                                             \
  }
#define STAGE_B(bufi, k0)                                                         \
  {                                                                               \
    _Pragma("unroll")                                                             \
    for (int j = 0; j < 4; ++j) {                                                 \
      __builtin_amdgcn_global_load_lds(                                           \
          (const __attribute__((address_space(1))) void*)(Bbase +                 \
              (size_t)(j * 64 + srow) * DDIM + (k0) + scol),                      \
          (__attribute__((address_space(3))) void*)(&sB[bufi][(j * 512 + t) * 8]),\
          16, 0, 0);                                                              \
    }                                                                             \
  }

  // prologue: K-tile 0 into buffer 0, drain, publish
  STAGE_A(0, 0);
  STAGE_B(0, 0);
  asm volatile("s_waitcnt vmcnt(0)" ::: "memory");
  __builtin_amdgcn_s_barrier();
  __builtin_amdgcn_sched_barrier(0);

  short8 af[4][2], ag[4][2], bf[4][2];

#define DS_A(dst, fmb)                                                             \
  _Pragma("unroll")                                                                \
  for (int fm = 0; fm < 4; ++fm)                                                   \
    _Pragma("unroll")                                                              \
    for (int ks = 0; ks < 2; ++ks) {                                               \
      const int row = wm * 128 + ((fmb) + fm) * 16 + lr;                           \
      dst[fm][ks] = *(const short8*)&sA[cur][row * BK + ((ks * 4 + lk) ^ (lr & 7)) * 8]; \
    }

#define DS_B2(fnb)                                                                 \
  _Pragma("unroll")                                                                \
  for (int fn = 0; fn < 2; ++fn)                                                   \
    _Pragma("unroll")                                                              \
    for (int ks = 0; ks < 2; ++ks) {                                               \
      const int row = wn * 64 + ((fnb) + fn) * 16 + lr;                            \
      bf[(fnb) + fn][ks] = *(const short8*)&sB[cur][row * BK + ((ks * 4 + lk) ^ (lr & 7)) * 8]; \
    }

#define MFMA16(A, fmb, fnb)                                                        \
  __builtin_amdgcn_s_setprio(1);                                                   \
  _Pragma("unroll")                                                                \
  for (int fm = 0; fm < 4; ++fm)                                                   \
    _Pragma("unroll")                                                              \
    for (int fn = 0; fn < 2; ++fn)                                                 \
      _Pragma("unroll")                                                            \
      for (int ks = 0; ks < 2; ++ks)                                               \
        acc[(fmb) + fm][(fnb) + fn] =                                              \
            __builtin_amdgcn_mfma_f32_16x16x32_bf16(A[fm][ks], bf[(fnb) + fn][ks], \
                                                    acc[(fmb) + fm][(fnb) + fn],   \
                                                    0, 0, 0);                      \
  __builtin_amdgcn_s_setprio(0);

#define SBAR __builtin_amdgcn_sched_barrier(0)
#define BAR  __builtin_amdgcn_s_barrier()

#pragma unroll
  for (int kt = 0; kt < KTILES; ++kt) {
    const int cur = kt & 1;
    const int nxt = cur ^ 1;
    // ---- P0: reads af(8)+bf01(4) pre-barrier; stage A of kt+1
    DS_A(af, 0); DS_B2(0);
    if (kt + 1 < KTILES) STAGE_A(nxt, (kt + 1) * BK);
    SBAR; BAR; SBAR;
    MFMA16(af, 0, 0);
    SBAR; BAR; SBAR;
    // ---- P1: reads bf23(4) pre-barrier; stage B of kt+1
    DS_B2(2);
    if (kt + 1 < KTILES) STAGE_B(nxt, (kt + 1) * BK);
    SBAR; BAR; SBAR;
    MFMA16(af, 0, 2);
    SBAR; BAR; SBAR;
    // ---- P2: reads ag(8) pre-barrier
    DS_A(ag, 4);
    SBAR; BAR; SBAR;
    MFMA16(ag, 4, 0);
    SBAR; BAR; SBAR;
    // ---- P3: drain kt+1 stages (2-3 phases of cover -> ~free)
    asm volatile("s_waitcnt vmcnt(0)" ::: "memory");
    SBAR; BAR; SBAR;
    MFMA16(ag, 4, 2);
    SBAR; BAR; SBAR;   // <- validity barrier for buffer nxt
  }

  // ---- Epilogue: e = exp(2*s); rowsums always, colsums when sym.
  // C/D layout (16x16x32): col = lane&15, row = (lane>>4)*4 + reg.
  float* rsum = (float*)&sA[0][0];        // 256 floats
  float* csum = rsum + BM;                // 256 floats
  if (t < BM) { rsum[t] = 0.0f; csum[t] = 0.0f; }
  __syncthreads();
  float c0 = 0.0f, c1 = 0.0f, c2 = 0.0f, c3 = 0.0f;
#pragma unroll
  for (int fm = 0; fm < 8; ++fm) {
#pragma unroll
    for (int r = 0; r < 4; ++r) {
      float e0 = __expf(2.0f * acc[fm][0][r]);
      float e1 = __expf(2.0f * acc[fm][1][r]);
      float e2 = __expf(2.0f * acc[fm][2][r]);
      float e3 = __expf(2.0f * acc[fm][3][r]);
      float v = e0 + e1 + e2 + e3;
      v += __shfl_xor(v, 1);
      v += __shfl_xor(v, 2);
      v += __shfl_xor(v, 4);
      v += __shfl_xor(v, 8);
      if (lr == 0) atomicAdd(&rsum[wm * 128 + fm * 16 + lk * 4 + r], v);
      c0 += e0; c1 += e1; c2 += e2; c3 += e3;
    }
  }
  if (sym) {
    c0 += __shfl_xor(c0, 16); c0 += __shfl_xor(c0, 32);
    c1 += __shfl_xor(c1, 16); c1 += __shfl_xor(c1, 32);
    c2 += __shfl_xor(c2, 16); c2 += __shfl_xor(c2, 32);
    c3 += __shfl_xor(c3, 16); c3 += __shfl_xor(c3, 32);
    if (l < 16) {   // one lane per column per wave; 2 waves (wm) share a col
      atomicAdd(&csum[wn * 64 +  0 + lr], c0);
      atomicAdd(&csum[wn * 64 + 16 + lr], c1);
      atomicAdd(&csum[wn * 64 + 32 + lr], c2);
      atomicAdd(&csum[wn * 64 + 48 + lr], c3);
    }
  }
  __syncthreads();
  if (t < BM) partial[(size_t)tn * NROWS + tm * BM + t] = rsum[t];
  if (sym && t < BM) partial[(size_t)tm * NROWS + tn * BM + t] = csum[t];
}

// Kernel 3: reduce partials, final loss.
// loss[i] = log(rowsum - e^2) - 2*dlr[i]
__global__ __launch_bounds__(256) void fin_kernel(const float* __restrict__ partial,
                                                  const float* __restrict__ dlr,
                                                  float* __restrict__ out) {
  const int i = blockIdx.x * 256 + threadIdx.x;
  float s = 0.0f;
#pragma unroll 8
  for (int p = 0; p < 64; ++p) s += partial[(size_t)p * NROWS + i];
  out[i] = logf(s - 7.38905609893065f) - 2.0f * dlr[i];
}

extern "C" void kernel_launch(void* const* d_in, const int* in_sizes, int n_in,
                              void* d_out, int out_size, void* d_ws, size_t ws_size,
                              hipStream_t stream) {
  const float* left = (const float*)d_in[0];
  const float* right = (const float*)d_in[1];
  float* out = (float*)d_out;

  unsigned short* Z = (unsigned short*)d_ws;                       // 16 MB
  char* p = (char*)d_ws + (size_t)ZROWS * DDIM * 2;
  float* dlr = (float*)p;                                          // 32 KB
  float* partial = (float*)(p + (size_t)NROWS * 4);                // 2 MB

  nrm_kernel<<<NROWS, 256, 0, stream>>>(left, right, Z, dlr);
  sim_kernel<<<NBLOCKS, 512, 0, stream>>>(Z, partial);
  fin_kernel<<<NROWS / 256, 256, 0, stream>>>(partial, dlr, out);
}